// Round 18
// baseline (367.657 us; speedup 1.0000x reference)
//
#include <hip/hip_runtime.h>
#include <cstdint>
#include <cmath>

#define N0G 100000
#define N1G 25000
#define N2G 6250
#define E0G 1600000
#define E1G 400000
#define E2G 100000
#define KCH 6
#define NCLS 40
#define RPB 512            // rows per bucket (9 bits local row)
#define NBLK 240           // binning blocks per stage
#define PAYB 17            // payload bits (col or edge idx < 131072)
#define PAYM ((1u << PAYB) - 1u)
#define SCT 16             // scan elems per thread
#define SCB (256 * SCT)    // scan elems per block
#define NST 5              // stages: L0,L1,L2,P0,P1

static inline int cdiv(long a, long b){ return (int)((a + b - 1) / b); }

struct BP {
  const int* row[NST]; const int* col[NST]; const float* pval[NST];
  unsigned* ebuf[NST]; int* cs[NST]; float* wv[NST]; int* rp[NST]; float* dinv[NST];
  const float* xsrc[NST]; float4* xsdst[NST];
  int E[NST], N[NST], nbkt[NST], chunk[NST], ghoff[NST], pool[NST], nb[NST], bsumoff[NST];
  int blkS[NST + 1], blkB[NST + 1];
};

// ================= batched deterministic bucket CSR build =================
__global__ __launch_bounds__(256) void k_phist_b(BP p, int* __restrict__ gh){
  int s = blockIdx.x / NBLK, c = blockIdx.x % NBLK;
  const int* row = p.row[s];
  int E = p.E[s], nbkt = p.nbkt[s], chunk = p.chunk[s];
  int* g = gh + p.ghoff[s];
  __shared__ int h[256];
  for (int i = threadIdx.x; i < nbkt; i += 256) h[i] = 0;
  __syncthreads();
  int e0 = c * chunk, e1 = min(E, e0 + chunk);
  for (int e = e0 + threadIdx.x; e < e1; e += 256)
    atomicAdd(&h[row[e] >> 9], 1);
  __syncthreads();
  for (int i = threadIdx.x; i < nbkt; i += 256)
    g[i * NBLK + c] = h[i];
}

__global__ __launch_bounds__(256) void k_scanA_b(BP p, const int* __restrict__ gh, int* __restrict__ bsum){
  int s = 0; while (s < NST - 1 && (int)blockIdx.x >= p.blkS[s + 1]) s++;
  int lb = blockIdx.x - p.blkS[s];
  int M = p.nbkt[s] * NBLK;
  const int* g = gh + p.ghoff[s];
  __shared__ int sh[256];
  int base = lb * SCB + threadIdx.x * SCT;
  int su = 0;
#pragma unroll
  for (int j = 0; j < SCT; j++){ int i = base + j; if (i < M) su += g[i]; }
  sh[threadIdx.x] = su; __syncthreads();
  for (int o = 128; o > 0; o >>= 1){
    if (threadIdx.x < o) sh[threadIdx.x] += sh[threadIdx.x + o];
    __syncthreads();
  }
  if (threadIdx.x == 0) bsum[p.bsumoff[s] + lb] = sh[0];
}

__global__ __launch_bounds__(256) void k_scanC_b(BP p, int* __restrict__ gh, const int* __restrict__ bsum){
  int s = 0; while (s < NST - 1 && (int)blockIdx.x >= p.blkS[s + 1]) s++;
  int lb = blockIdx.x - p.blkS[s];
  int M = p.nbkt[s] * NBLK;
  int* g = gh + p.ghoff[s];
  __shared__ int sh[256];
  __shared__ int blockoff;
  if (threadIdx.x == 0){
    int off = 0;
    if (p.nb[s] > 1){
      const int* bs = bsum + p.bsumoff[s];
      for (int j = 0; j < lb; j++) off += bs[j];
    }
    blockoff = off;
  }
  int base = lb * SCB + threadIdx.x * SCT;
  int v[SCT]; int su = 0;
#pragma unroll
  for (int j = 0; j < SCT; j++){ int i = base + j; v[j] = (i < M) ? g[i] : 0; su += v[j]; }
  sh[threadIdx.x] = su;
  __syncthreads();
  for (int o = 1; o < 256; o <<= 1){
    int t = (threadIdx.x >= o) ? sh[threadIdx.x - o] : 0;
    __syncthreads();
    sh[threadIdx.x] += t;
    __syncthreads();
  }
  int excl = blockoff + sh[threadIdx.x] - su;
#pragma unroll
  for (int j = 0; j < SCT; j++){
    int i = base + j;
    if (i < M){ g[i] = excl; excl += v[j]; }
  }
  if (lb == 0 && threadIdx.x == 0) p.rp[s][p.N[s]] = p.E[s];
}

__global__ __launch_bounds__(256) void k_pscatter_b(BP p, const int* __restrict__ gh){
  int s = blockIdx.x / NBLK, c = blockIdx.x % NBLK;
  const int* row = p.row[s]; const int* col = p.col[s];
  int E = p.E[s], nbkt = p.nbkt[s], chunk = p.chunk[s], pool = p.pool[s];
  const int* g = gh + p.ghoff[s];
  unsigned* ebuf = p.ebuf[s];
  __shared__ int cur[256];
  for (int i = threadIdx.x; i < nbkt; i += 256) cur[i] = g[i * NBLK + c];
  __syncthreads();
  int e0 = c * chunk, e1 = min(E, e0 + chunk);
  for (int e = e0 + threadIdx.x; e < e1; e += 256){
    int r = row[e];
    int dst = atomicAdd(&cur[r >> 9], 1);
    unsigned pay = pool ? (unsigned)e : (unsigned)col[e];
    ebuf[dst] = ((unsigned)(r & 511) << PAYB) | pay;
  }
}

__global__ __launch_bounds__(512) void k_bfinal_b(BP p, const int* __restrict__ gh){
  int s = 0; while (s < NST - 1 && (int)blockIdx.x >= p.blkB[s + 1]) s++;
  int b = blockIdx.x - p.blkB[s];
  const int* g = gh + p.ghoff[s];
  const unsigned* ebuf = p.ebuf[s];
  int nbkt = p.nbkt[s], N = p.N[s], E = p.E[s], pool = p.pool[s];
  int* cs = p.cs[s]; float* wv = p.wv[s];
  int* rp = p.rp[s]; float* dinv = p.dinv[s];
  const int* pcol = p.col[s]; const float* pval = p.pval[s];
  __shared__ int h[512];
  __shared__ int cur[512];
  int e0 = g[b * NBLK];
  int e1 = (b + 1 < nbkt) ? g[(b + 1) * NBLK] : E;
  int r0 = b * RPB;
  int t = threadIdx.x;
  h[t] = 0;
  __syncthreads();
  for (int e = e0 + t; e < e1; e += 512)
    atomicAdd(&h[ebuf[e] >> PAYB], 1);
  __syncthreads();
  int cnt = h[t];
  __syncthreads();
  for (int o = 1; o < 512; o <<= 1){
    int tmp = (t >= o) ? h[t - o] : 0;
    __syncthreads();
    h[t] += tmp;
    __syncthreads();
  }
  int excl = h[t] - cnt;
  cur[t] = excl;
  int n = r0 + t;
  if (n < N){
    rp[n] = e0 + excl;
    if (!pool){
      float d = cnt > 0 ? rsqrtf((float)cnt) : 0.f;
      dinv[n] = d;
      if (p.xsrc[s]){                // stage 0: fused prescale xs0 = d * x row (F=3)
        const float* x = p.xsrc[s];
        p.xsdst[s][n] = make_float4(d * x[n * 3 + 0], d * x[n * 3 + 1], d * x[n * 3 + 2], 0.f);
      }
    }
  }
  __syncthreads();
  for (int e = e0 + t; e < e1; e += 512){
    unsigned u = ebuf[e];
    int pp = atomicAdd(&cur[u >> PAYB], 1);
    int dst = e0 + pp;
    if (pool){
      int ei = (int)(u & PAYM);
      cs[dst] = pcol[ei]; wv[dst] = pval[ei];
    } else {
      cs[dst] = (int)(u & PAYM);
    }
  }
}

// ================= CSR gathers (prescaled source, edge-split lanes) =================
__global__ __launch_bounds__(256) void k_gather3(const int* __restrict__ rp, const int* __restrict__ cs,
                          const float4* __restrict__ xs, const float* __restrict__ dinv,
                          const float* __restrict__ sub, float* __restrict__ dst,
                          float4* __restrict__ xs_out, int N, float scale){
  int tid = blockIdx.x * 256 + threadIdx.x;
  int n = tid >> 3, q = tid & 7;
  if (n >= N) return;
  int e0 = rp[n], e1 = rp[n + 1];
  float a0 = 0.f, a1 = 0.f, a2 = 0.f;
  for (int e = e0 + q; e < e1; e += 8){
    float4 v = xs[cs[e]];
    a0 += v.x; a1 += v.y; a2 += v.z;
  }
  a0 += __shfl_xor(a0, 1); a1 += __shfl_xor(a1, 1); a2 += __shfl_xor(a2, 1);
  a0 += __shfl_xor(a0, 2); a1 += __shfl_xor(a1, 2); a2 += __shfl_xor(a2, 2);
  a0 += __shfl_xor(a0, 4); a1 += __shfl_xor(a1, 4); a2 += __shfl_xor(a2, 4);
  if (q == 0){
    float dn = dinv[n];
    float m = -scale * dn;
    float r0 = m * a0, r1 = m * a1, r2 = m * a2;
    if (sub){ r0 -= sub[n * 3 + 0]; r1 -= sub[n * 3 + 1]; r2 -= sub[n * 3 + 2]; }
    dst[n * 3 + 0] = r0; dst[n * 3 + 1] = r1; dst[n * 3 + 2] = r2;
    if (xs_out) xs_out[n] = make_float4(dn * r0, dn * r1, dn * r2, 0.f);
  }
}

template<int F>
__global__ __launch_bounds__(256) void k_gatherT(const int* __restrict__ rp, const int* __restrict__ cs,
                          const float4* __restrict__ xs, const float* __restrict__ dinv,
                          const float* __restrict__ sub, float* __restrict__ dst,
                          float4* __restrict__ xs_out, int N, float scale){
  constexpr int L = F / 4;
  constexpr int G = 4 * L;
  int tid = blockIdx.x * 256 + threadIdx.x;
  int n = tid / G, q = tid % G;
  if (n >= N) return;
  int f4 = q % L, es = q / L;
  int e0 = rp[n], e1 = rp[n + 1];
  float4 acc = make_float4(0.f, 0.f, 0.f, 0.f);
  for (int e = e0 + es; e < e1; e += 4){
    float4 v = xs[(long)cs[e] * L + f4];
    acc.x += v.x; acc.y += v.y; acc.z += v.z; acc.w += v.w;
  }
  acc.x += __shfl_xor(acc.x, L);     acc.y += __shfl_xor(acc.y, L);
  acc.z += __shfl_xor(acc.z, L);     acc.w += __shfl_xor(acc.w, L);
  acc.x += __shfl_xor(acc.x, 2 * L); acc.y += __shfl_xor(acc.y, 2 * L);
  acc.z += __shfl_xor(acc.z, 2 * L); acc.w += __shfl_xor(acc.w, 2 * L);
  if (es == 0){
    float dn = dinv[n];
    float m = -scale * dn;
    float4 r = make_float4(m * acc.x, m * acc.y, m * acc.z, m * acc.w);
    if (sub){
      float4 sv = ((const float4*)sub)[(long)n * L + f4];
      r.x -= sv.x; r.y -= sv.y; r.z -= sv.z; r.w -= sv.w;
    }
    ((float4*)dst)[(long)n * L + f4] = r;
    if (xs_out) xs_out[(long)n * L + f4] = make_float4(dn * r.x, dn * r.y, dn * r.z, dn * r.w);
  }
}

// pool gather; optionally emits prescaled xs for the next graph layer
template<int F>
__global__ __launch_bounds__(256) void k_gatherP(const int* __restrict__ rp, const int* __restrict__ cs,
                          const float* __restrict__ wv, const float* __restrict__ h,
                          float* __restrict__ dst, int N,
                          const float* __restrict__ dinvN, float4* __restrict__ xsN){
  constexpr int L = F / 4;
  int tid = blockIdx.x * 256 + threadIdx.x;
  int n = tid / L, q = tid % L;
  if (n >= N) return;
  const float4* h4 = (const float4*)h;
  int e0 = rp[n], e1 = rp[n + 1];
  float4 acc = make_float4(0.f, 0.f, 0.f, 0.f);
  for (int e = e0; e < e1; e++){
    int c = cs[e];
    float w = wv[e];
    float4 v = h4[(long)c * L + q];
    acc.x = fmaf(w, v.x, acc.x); acc.y = fmaf(w, v.y, acc.y);
    acc.z = fmaf(w, v.z, acc.z); acc.w = fmaf(w, v.w, acc.w);
  }
  ((float4*)dst)[(long)n * L + q] = acc;
  if (xsN){
    float dn = dinvN[n];
    xsN[(long)n * L + q] = make_float4(dn * acc.x, dn * acc.y, dn * acc.z, dn * acc.w);
  }
}

// ================= dense cheb contraction, LDS-tiled =================
template<int F, int FO, int R, bool RELU>
__global__ __launch_bounds__(256) void k_cheb_tile(const float* __restrict__ x, const float* __restrict__ T, int N,
                           const float* __restrict__ W, const float* __restrict__ b,
                           float* __restrict__ out){
  constexpr int OQ4  = FO / 4;
  constexpr int NSUB = 256 / OQ4;
  constexpr int NT   = NSUB * R;
  constexpr int F6   = KCH * F;
  int n0 = blockIdx.x * NT;
  int o4   = threadIdx.x % OQ4;
  int nsub = threadIdx.x / OQ4;
  const float4* W4 = (const float4*)W;       // [F6][OQ4]
  float4 acc[R];
  float4 bb = ((const float4*)b)[o4];
#pragma unroll
  for (int r = 0; r < R; r++) acc[r] = bb;

  if constexpr (F == 3){
    constexpr int PITCH = F6 + 2;
    __shared__ float X[NT * PITCH];
    for (int i = threadIdx.x; i < NT * F6; i += 256){
      int k = i / (NT * 3);
      int idx = i - k * (NT * 3);
      const float* src = (k == 0) ? x : (T + (size_t)(k - 1) * N * 3);
      int node = idx / 3, j = idx - node * 3;
      float v = (n0 + node < N) ? src[(long)n0 * 3 + idx] : 0.f;
      X[node * PITCH + k * 3 + j] = v;
    }
    __syncthreads();
#pragma unroll
    for (int f = 0; f < F6; f++){
      float4 w = W4[(long)f * OQ4 + o4];
#pragma unroll
      for (int r = 0; r < R; r++){
        float v = X[(nsub * R + r) * PITCH + f];
        acc[r].x = fmaf(v, w.x, acc[r].x); acc[r].y = fmaf(v, w.y, acc[r].y);
        acc[r].z = fmaf(v, w.z, acc[r].z); acc[r].w = fmaf(v, w.w, acc[r].w);
      }
    }
  } else {
    constexpr int L  = F / 4;
    constexpr int P4 = F6 / 4 + 1;
    __shared__ float4 X[NT * P4];
    for (int i = threadIdx.x; i < NT * KCH * L; i += 256){
      int k = i / (NT * L);
      int idx = i - k * (NT * L);
      int node = idx / L, q = idx - node * L;
      const float4* src4 = (const float4*)((k == 0) ? x : (T + (size_t)(k - 1) * N * F));
      float4 v = make_float4(0.f, 0.f, 0.f, 0.f);
      if (n0 + node < N) v = src4[(long)n0 * L + idx];
      X[node * P4 + k * L + q] = v;
    }
    __syncthreads();
#pragma unroll 4
    for (int f4 = 0; f4 < F6 / 4; f4++){
      float4 w0 = W4[(long)(4 * f4 + 0) * OQ4 + o4];
      float4 w1 = W4[(long)(4 * f4 + 1) * OQ4 + o4];
      float4 w2 = W4[(long)(4 * f4 + 2) * OQ4 + o4];
      float4 w3 = W4[(long)(4 * f4 + 3) * OQ4 + o4];
#pragma unroll
      for (int r = 0; r < R; r++){
        float4 hv = X[(nsub * R + r) * P4 + f4];
        acc[r].x = fmaf(hv.x, w0.x, acc[r].x); acc[r].y = fmaf(hv.x, w0.y, acc[r].y);
        acc[r].z = fmaf(hv.x, w0.z, acc[r].z); acc[r].w = fmaf(hv.x, w0.w, acc[r].w);
        acc[r].x = fmaf(hv.y, w1.x, acc[r].x); acc[r].y = fmaf(hv.y, w1.y, acc[r].y);
        acc[r].z = fmaf(hv.y, w1.z, acc[r].z); acc[r].w = fmaf(hv.y, w1.w, acc[r].w);
        acc[r].x = fmaf(hv.z, w2.x, acc[r].x); acc[r].y = fmaf(hv.z, w2.y, acc[r].y);
        acc[r].z = fmaf(hv.z, w2.z, acc[r].z); acc[r].w = fmaf(hv.z, w2.w, acc[r].w);
        acc[r].x = fmaf(hv.w, w3.x, acc[r].x); acc[r].y = fmaf(hv.w, w3.y, acc[r].y);
        acc[r].z = fmaf(hv.w, w3.z, acc[r].z); acc[r].w = fmaf(hv.w, w3.w, acc[r].w);
      }
    }
  }

#pragma unroll
  for (int r = 0; r < R; r++){
    int n = n0 + nsub * R + r;
    if (n < N){
      float4 o = acc[r];
      if (RELU){
        o.x = fmaxf(o.x, 0.f); o.y = fmaxf(o.y, 0.f);
        o.z = fmaxf(o.z, 0.f); o.w = fmaxf(o.w, 0.f);
      }
      ((float4*)out)[(long)n * OQ4 + o4] = o;
    }
  }
}

// ================= hidden GEMM + global max (read h2 once, atomic-free 2-level max) =================
// 512 threads: thread = 1 float4 output x 4 nodes; halves of block do nodes 0-3 / 4-7.
// Each half writes its own pmax row -> 2*gridDim rows, reduced by k_hidden2.
#define HNT 8
__global__ __launch_bounds__(512) void k_hidden1(const float* __restrict__ h2, const float* __restrict__ Wh,
                                                 float4* __restrict__ pmax, int N){
  __shared__ float4 sh4[HNT * 32];       // 4 KB: 8 nodes x 32 float4
  int n0 = blockIdx.x * HNT;
  for (int i = threadIdx.x; i < HNT * 32; i += 512){
    int n = i >> 5;
    float4 v = make_float4(0.f, 0.f, 0.f, 0.f);
    if (n0 + n < N) v = ((const float4*)h2)[(long)(n0 + n) * 32 + (i & 31)];
    sh4[i] = v;
  }
  __syncthreads();
  int o4   = threadIdx.x & 255;
  int half = threadIdx.x >> 8;           // 0 or 1 -> nodes 0-3 / 4-7
  const float4* Wh4 = (const float4*)Wh;
  float4 acc[4];
#pragma unroll
  for (int j = 0; j < 4; j++) acc[j] = make_float4(0.f, 0.f, 0.f, 0.f);
#pragma unroll 2
  for (int f4 = 0; f4 < 32; f4++){
    float4 w0 = Wh4[(long)(4 * f4 + 0) * 256 + o4];
    float4 w1 = Wh4[(long)(4 * f4 + 1) * 256 + o4];
    float4 w2 = Wh4[(long)(4 * f4 + 2) * 256 + o4];
    float4 w3 = Wh4[(long)(4 * f4 + 3) * 256 + o4];
#pragma unroll
    for (int j = 0; j < 4; j++){
      float4 hv = sh4[(half * 4 + j) * 32 + f4];
      acc[j].x = fmaf(hv.x, w0.x, acc[j].x); acc[j].y = fmaf(hv.x, w0.y, acc[j].y);
      acc[j].z = fmaf(hv.x, w0.z, acc[j].z); acc[j].w = fmaf(hv.x, w0.w, acc[j].w);
      acc[j].x = fmaf(hv.y, w1.x, acc[j].x); acc[j].y = fmaf(hv.y, w1.y, acc[j].y);
      acc[j].z = fmaf(hv.y, w1.z, acc[j].z); acc[j].w = fmaf(hv.y, w1.w, acc[j].w);
      acc[j].x = fmaf(hv.z, w2.x, acc[j].x); acc[j].y = fmaf(hv.z, w2.y, acc[j].y);
      acc[j].z = fmaf(hv.z, w2.z, acc[j].z); acc[j].w = fmaf(hv.z, w2.w, acc[j].w);
      acc[j].x = fmaf(hv.w, w3.x, acc[j].x); acc[j].y = fmaf(hv.w, w3.y, acc[j].y);
      acc[j].z = fmaf(hv.w, w3.z, acc[j].z); acc[j].w = fmaf(hv.w, w3.w, acc[j].w);
    }
  }
  float4 m = make_float4(-INFINITY, -INFINITY, -INFINITY, -INFINITY);
#pragma unroll
  for (int j = 0; j < 4; j++){
    if (n0 + half * 4 + j < N){
      m.x = fmaxf(m.x, acc[j].x); m.y = fmaxf(m.y, acc[j].y);
      m.z = fmaxf(m.z, acc[j].z); m.w = fmaxf(m.w, acc[j].w);
    }
  }
  pmax[((long)blockIdx.x * 2 + half) * 256 + o4] = m;   // coalesced, atomic-free
}

// 32 blocks x 256 threads: block handles 8 float4 outputs; 32 row-lanes each.
__global__ __launch_bounds__(256) void k_hidden2(const float4* __restrict__ pmax, const float* __restrict__ bh,
                                                 float* __restrict__ maxed, int nb){
  __shared__ float4 red[256];
  int lo4 = threadIdx.x & 7;
  int rl  = threadIdx.x >> 3;
  int o4  = blockIdx.x * 8 + lo4;
  float4 m = make_float4(-INFINITY, -INFINITY, -INFINITY, -INFINITY);
  for (int r = rl; r < nb; r += 32){
    float4 v = pmax[(long)r * 256 + o4];
    m.x = fmaxf(m.x, v.x); m.y = fmaxf(m.y, v.y);
    m.z = fmaxf(m.z, v.z); m.w = fmaxf(m.w, v.w);
  }
  red[threadIdx.x] = m;
  __syncthreads();
  for (int off = 128; off >= 8; off >>= 1){
    if (threadIdx.x < off){
      float4 o = red[threadIdx.x + off];
      float4 c = red[threadIdx.x];
      c.x = fmaxf(c.x, o.x); c.y = fmaxf(c.y, o.y);
      c.z = fmaxf(c.z, o.z); c.w = fmaxf(c.w, o.w);
      red[threadIdx.x] = c;
    }
    __syncthreads();
  }
  if (threadIdx.x < 8){
    float4 mm = red[threadIdx.x];
    float4 b4 = ((const float4*)bh)[o4];
    ((float4*)maxed)[o4] = make_float4(mm.x + b4.x, mm.y + b4.y, mm.z + b4.z, mm.w + b4.w);
  }
}

__global__ __launch_bounds__(64) void k_final(const float* __restrict__ maxed, const float* __restrict__ Wl,
                        const float* __restrict__ bl, float* __restrict__ out){
  int c = blockIdx.x;
  int l = threadIdx.x;
  float acc = 0.f;
  for (int o = l; o < 1024; o += 64)
    acc = fmaf(maxed[o], Wl[o * NCLS + c], acc);
  for (int off = 32; off > 0; off >>= 1)
    acc += __shfl_down(acc, off);
  if (l == 0) out[c] = acc + bl[c];
}

// ================= flow drivers (xs already prescaled) =================
template<int F, int FO, int R, bool RELU>
static void run_flowT(const int* rp, const int* cs, const float* dinv, int N,
                      const float* x, const float* W, const float* b, float* out,
                      float* T, float4* xin, float4* xout, hipStream_t s){
  const float* sub = nullptr; float scale = 1.f;
  const float* srcRaw = x;
  for (int k = 1; k < KCH; k++){
    float* Tk = T + (size_t)(k - 1) * N * F;
    float4* xo = (k == KCH - 1) ? nullptr : xout;
    k_gatherT<F><<<cdiv((long)N * F, 256), 256, 0, s>>>(rp, cs, xin, dinv, sub, Tk, xo, N, scale);
    sub = srcRaw; srcRaw = Tk; scale = 2.f;
    float4* t = xin; xin = xout; xout = t;
  }
  constexpr int NTC = (256 / (FO / 4)) * R;
  k_cheb_tile<F, FO, R, RELU><<<cdiv(N, NTC), 256, 0, s>>>(x, T, N, W, b, out);
}

extern "C" void kernel_launch(void* const* d_in, const int* in_sizes, int n_in,
                              void* d_out, int out_size, void* d_ws, size_t ws_size,
                              hipStream_t stream){
  const float* pos = (const float*)d_in[0];
  const int*   ei0 = (const int*)d_in[1];
  const int*   ei1 = (const int*)d_in[2];
  const int*   ei2 = (const int*)d_in[3];
  const int*   p0r = (const int*)d_in[4];
  const int*   p0c = (const int*)d_in[5];
  const float* p0v = (const float*)d_in[6];
  const int*   p1r = (const int*)d_in[7];
  const int*   p1c = (const int*)d_in[8];
  const float* p1v = (const float*)d_in[9];
  const float* W0  = (const float*)d_in[10]; const float* b0 = (const float*)d_in[11];
  const float* W1  = (const float*)d_in[12]; const float* b1 = (const float*)d_in[13];
  const float* W2  = (const float*)d_in[14]; const float* b2 = (const float*)d_in[15];
  const float* Wh  = (const float*)d_in[16]; const float* bh = (const float*)d_in[17];
  const float* Wl  = (const float*)d_in[18]; const float* bl = (const float*)d_in[19];
  float* out = (float*)d_out;

  // ---- workspace layout (float units), ~12.33M floats ----
  float* TB = (float*)d_ws;                  // 4.0M : ebufs (build) overlay; per-layer T region; pmax overlay
  float* hA = TB + 4000000;                  // 3.2M : L0 out [N0,32]; L1 out; L2 out [N2,128]
  float* hB = hA + 3200000;                  // 1.6M : xs ping-pong regions
  float* hC = hB + 1600000;                  // 0.8M : pool outs [N1,32]/[N2,64]
  int* cs0   = (int*)(hC + 800000);          // 1.6M
  int* cs1   = cs0 + 1600000;                // 400K
  int* cs2   = cs1 + 400000;                 // 100K
  int* csP0  = cs2 + 100000;                 // 100K
  int* csP1  = csP0 + 100000;                // 25K
  float* wvP0 = (float*)(csP1 + 25000);      // 100K
  float* wvP1 = wvP0 + 100000;               // 25K
  int* rp0  = (int*)(wvP1 + 25000);          // 100001
  int* rp1  = rp0 + 100001;                  // 25001
  int* rp2  = rp1 + 25001;                   // 6251
  int* rpP0 = rp2 + 6251;                    // 25001
  int* rpP1 = rpP0 + 25001;                  // 6251
  float* dv0 = (float*)(rpP1 + 6251);        // 100000
  float* dv1 = dv0 + 100000;                 // 25000
  float* dv2 = dv1 + 25000;                  // 6250
  int* gh   = (int*)(dv2 + 6250);            // 76800
  int* bsum = gh + 76800;                    // 80
  float* maxed = (float*)(bsum + 80);        // 1024

  // ebufs overlay the TB region (dead before any gather/T write)
  unsigned* eb0  = (unsigned*)TB;            // 1.6M
  unsigned* eb1  = eb0 + 1600000;            // 400K
  unsigned* eb2  = eb1 + 400000;             // 100K
  unsigned* ebP0 = eb2 + 100000;             // 100K
  unsigned* ebP1 = ebP0 + 100000;            // 25K

  // ---- batched CSR builds (stage 0 fuses xs0 = dinv*pos into hB) ----
  BP bp{};
  const int* rows[NST] = {ei0, ei1, ei2, p0r, p1r};
  const int* cols[NST] = {ei0 + E0G, ei1 + E1G, ei2 + E2G, p0c, p1c};
  const float* pvals[NST] = {nullptr, nullptr, nullptr, p0v, p1v};
  unsigned* ebufs[NST] = {eb0, eb1, eb2, ebP0, ebP1};
  int* css[NST] = {cs0, cs1, cs2, csP0, csP1};
  float* wvs[NST] = {nullptr, nullptr, nullptr, wvP0, wvP1};
  int* rps[NST] = {rp0, rp1, rp2, rpP0, rpP1};
  float* dvs[NST] = {dv0, dv1, dv2, nullptr, nullptr};
  int Es[NST] = {E0G, E1G, E2G, N0G, N1G};
  int Ns[NST] = {N0G, N1G, N2G, N1G, N2G};
  int pools[NST] = {0, 0, 0, 1, 1};
  int ghacc = 0, scanacc = 0, bacc = 0;
  bp.blkS[0] = 0; bp.blkB[0] = 0;
  for (int s = 0; s < NST; s++){
    bp.row[s] = rows[s]; bp.col[s] = cols[s]; bp.pval[s] = pvals[s];
    bp.ebuf[s] = ebufs[s]; bp.cs[s] = css[s]; bp.wv[s] = wvs[s];
    bp.rp[s] = rps[s]; bp.dinv[s] = dvs[s];
    bp.xsrc[s] = (s == 0) ? pos : nullptr;
    bp.xsdst[s] = (s == 0) ? (float4*)hB : nullptr;
    bp.E[s] = Es[s]; bp.N[s] = Ns[s]; bp.pool[s] = pools[s];
    bp.nbkt[s] = cdiv(Ns[s], RPB);
    bp.chunk[s] = cdiv(Es[s], NBLK);
    bp.ghoff[s] = ghacc; ghacc += bp.nbkt[s] * NBLK;
    bp.nb[s] = cdiv(bp.nbkt[s] * NBLK, SCB);
    bp.bsumoff[s] = s * 16;
    scanacc += bp.nb[s]; bp.blkS[s + 1] = scanacc;
    bacc += bp.nbkt[s]; bp.blkB[s + 1] = bacc;
  }

  k_phist_b<<<NST * NBLK, 256, 0, stream>>>(bp, gh);
  k_scanA_b<<<scanacc, 256, 0, stream>>>(bp, gh, bsum);
  k_scanC_b<<<scanacc, 256, 0, stream>>>(bp, gh, bsum);
  k_pscatter_b<<<NST * NBLK, 256, 0, stream>>>(bp, gh);
  k_bfinal_b<<<bacc, 512, 0, stream>>>(bp, gh);

  // ---- layer 0: cheb(pos) -> hA [N0,32]; T=1.5M in TB; xs ping-pong in hB (xs0 pre-filled) ----
  {
    float4* xin = (float4*)hB; float4* xout = (float4*)(hB + 400000);
    const float* sub = nullptr; float scale = 1.f;
    const float* srcRaw = pos;
    for (int k = 1; k < KCH; k++){
      float* Tk = TB + (size_t)(k - 1) * N0G * 3;
      float4* xo = (k == KCH - 1) ? nullptr : xout;
      k_gather3<<<cdiv((long)N0G * 8, 256), 256, 0, stream>>>(rp0, cs0, xin, dv0, sub, Tk, xo, N0G, scale);
      sub = srcRaw; srcRaw = Tk; scale = 2.f;
      float4* t = xin; xin = xout; xout = t;
    }
    k_cheb_tile<3, 32, 2, true><<<cdiv(N0G, 64), 256, 0, stream>>>(pos, TB, N0G, W0, b0, hA);
  }

  // ---- pool 0: hA -> hC [N1,32]; fused prescale xs1 = dv1*out -> hB ----
  k_gatherP<32><<<cdiv((long)N1G * 8, 256), 256, 0, stream>>>(rpP0, csP0, wvP0, hA, hC, N1G,
                                                              dv1, (float4*)hB);

  // ---- layer 1: cheb(hC) -> hA [N1,64]; T=4.0M in TB; xs ping-pong hB/hB+800K ----
  run_flowT<32, 64, 2, true>(rp1, cs1, dv1, N1G, hC, W1, b1, hA,
                             TB, (float4*)hB, (float4*)(hB + 800000), stream);

  // ---- pool 1: hA -> hC [N2,64]; fused prescale xs2 = dv2*out -> hB ----
  k_gatherP<64><<<cdiv((long)N2G * 16, 256), 256, 0, stream>>>(rpP1, csP1, wvP1, hA, hC, N2G,
                                                               dv2, (float4*)hB);

  // ---- layer 2: cheb(hC) -> hA [N2,128]; T=2.0M in TB; xs ping-pong hB/hB+400K ----
  run_flowT<64, 128, 2, false>(rp2, cs2, dv2, N2G, hC, W2, b2, hA,
                               TB, (float4*)hB, (float4*)(hB + 400000), stream);

  // ---- hidden GEMM + global max: h2 read once, pmax overlay on TB (dead) ----
  int nbH = cdiv(N2G, HNT);                  // 782 blocks, 2 pmax rows each
  float4* pmax = (float4*)TB;                // 1564*256 float4 = 6.4 MB, fits in TB
  k_hidden1<<<nbH, 512, 0, stream>>>(hA, Wh, pmax, N2G);
  k_hidden2<<<32, 256, 0, stream>>>(pmax, bh, maxed, nbH * 2);

  // ---- classifier ----
  k_final<<<NCLS, 64, 0, stream>>>(maxed, Wl, bl, out);
}

// Round 19
// 335.594 us; speedup vs baseline: 1.0955x; 1.0955x over previous
//
#include <hip/hip_runtime.h>
#include <cstdint>
#include <cmath>

#define N0G 100000
#define N1G 25000
#define N2G 6250
#define E0G 1600000
#define E1G 400000
#define E2G 100000
#define KCH 6
#define NCLS 40
#define RPB 512            // rows per bucket (9 bits local row)
#define NBLK 240           // binning blocks per stage
#define PAYB 17            // payload bits (col or edge idx < 131072)
#define PAYM ((1u << PAYB) - 1u)
#define SCT 16             // scan elems per thread
#define SCB (256 * SCT)    // scan elems per block
#define NST 5              // stages: L0,L1,L2,P0,P1

static inline int cdiv(long a, long b){ return (int)((a + b - 1) / b); }

struct BP {
  const int* row[NST]; const int* col[NST]; const float* pval[NST];
  unsigned* ebuf[NST]; int* cs[NST]; float* wv[NST]; int* rp[NST]; float* dinv[NST];
  const float* xsrc[NST]; float4* xsdst[NST];
  int E[NST], N[NST], nbkt[NST], chunk[NST], ghoff[NST], pool[NST], nb[NST], bsumoff[NST];
  int blkS[NST + 1], blkB[NST + 1];
};

// ================= batched deterministic bucket CSR build =================
__global__ __launch_bounds__(256) void k_phist_b(BP p, int* __restrict__ gh){
  int s = blockIdx.x / NBLK, c = blockIdx.x % NBLK;
  const int* row = p.row[s];
  int E = p.E[s], nbkt = p.nbkt[s], chunk = p.chunk[s];
  int* g = gh + p.ghoff[s];
  __shared__ int h[256];
  for (int i = threadIdx.x; i < nbkt; i += 256) h[i] = 0;
  __syncthreads();
  int e0 = c * chunk, e1 = min(E, e0 + chunk);
  for (int e = e0 + threadIdx.x; e < e1; e += 256)
    atomicAdd(&h[row[e] >> 9], 1);
  __syncthreads();
  for (int i = threadIdx.x; i < nbkt; i += 256)
    g[i * NBLK + c] = h[i];
}

__global__ __launch_bounds__(256) void k_scanA_b(BP p, const int* __restrict__ gh, int* __restrict__ bsum){
  int s = 0; while (s < NST - 1 && (int)blockIdx.x >= p.blkS[s + 1]) s++;
  int lb = blockIdx.x - p.blkS[s];
  int M = p.nbkt[s] * NBLK;
  const int* g = gh + p.ghoff[s];
  __shared__ int sh[256];
  int base = lb * SCB + threadIdx.x * SCT;
  int su = 0;
#pragma unroll
  for (int j = 0; j < SCT; j++){ int i = base + j; if (i < M) su += g[i]; }
  sh[threadIdx.x] = su; __syncthreads();
  for (int o = 128; o > 0; o >>= 1){
    if (threadIdx.x < o) sh[threadIdx.x] += sh[threadIdx.x + o];
    __syncthreads();
  }
  if (threadIdx.x == 0) bsum[p.bsumoff[s] + lb] = sh[0];
}

__global__ __launch_bounds__(256) void k_scanC_b(BP p, int* __restrict__ gh, const int* __restrict__ bsum){
  int s = 0; while (s < NST - 1 && (int)blockIdx.x >= p.blkS[s + 1]) s++;
  int lb = blockIdx.x - p.blkS[s];
  int M = p.nbkt[s] * NBLK;
  int* g = gh + p.ghoff[s];
  __shared__ int sh[256];
  __shared__ int blockoff;
  if (threadIdx.x == 0){
    int off = 0;
    if (p.nb[s] > 1){
      const int* bs = bsum + p.bsumoff[s];
      for (int j = 0; j < lb; j++) off += bs[j];
    }
    blockoff = off;
  }
  int base = lb * SCB + threadIdx.x * SCT;
  int v[SCT]; int su = 0;
#pragma unroll
  for (int j = 0; j < SCT; j++){ int i = base + j; v[j] = (i < M) ? g[i] : 0; su += v[j]; }
  sh[threadIdx.x] = su;
  __syncthreads();
  for (int o = 1; o < 256; o <<= 1){
    int t = (threadIdx.x >= o) ? sh[threadIdx.x - o] : 0;
    __syncthreads();
    sh[threadIdx.x] += t;
    __syncthreads();
  }
  int excl = blockoff + sh[threadIdx.x] - su;
#pragma unroll
  for (int j = 0; j < SCT; j++){
    int i = base + j;
    if (i < M){ g[i] = excl; excl += v[j]; }
  }
  if (lb == 0 && threadIdx.x == 0) p.rp[s][p.N[s]] = p.E[s];
}

__global__ __launch_bounds__(256) void k_pscatter_b(BP p, const int* __restrict__ gh){
  int s = blockIdx.x / NBLK, c = blockIdx.x % NBLK;
  const int* row = p.row[s]; const int* col = p.col[s];
  int E = p.E[s], nbkt = p.nbkt[s], chunk = p.chunk[s], pool = p.pool[s];
  const int* g = gh + p.ghoff[s];
  unsigned* ebuf = p.ebuf[s];
  __shared__ int cur[256];
  for (int i = threadIdx.x; i < nbkt; i += 256) cur[i] = g[i * NBLK + c];
  __syncthreads();
  int e0 = c * chunk, e1 = min(E, e0 + chunk);
  for (int e = e0 + threadIdx.x; e < e1; e += 256){
    int r = row[e];
    int dst = atomicAdd(&cur[r >> 9], 1);
    unsigned pay = pool ? (unsigned)e : (unsigned)col[e];
    ebuf[dst] = ((unsigned)(r & 511) << PAYB) | pay;
  }
}

__global__ __launch_bounds__(512) void k_bfinal_b(BP p, const int* __restrict__ gh){
  int s = 0; while (s < NST - 1 && (int)blockIdx.x >= p.blkB[s + 1]) s++;
  int b = blockIdx.x - p.blkB[s];
  const int* g = gh + p.ghoff[s];
  const unsigned* ebuf = p.ebuf[s];
  int nbkt = p.nbkt[s], N = p.N[s], E = p.E[s], pool = p.pool[s];
  int* cs = p.cs[s]; float* wv = p.wv[s];
  int* rp = p.rp[s]; float* dinv = p.dinv[s];
  const int* pcol = p.col[s]; const float* pval = p.pval[s];
  __shared__ int h[512];
  __shared__ int cur[512];
  int e0 = g[b * NBLK];
  int e1 = (b + 1 < nbkt) ? g[(b + 1) * NBLK] : E;
  int r0 = b * RPB;
  int t = threadIdx.x;
  h[t] = 0;
  __syncthreads();
  for (int e = e0 + t; e < e1; e += 512)
    atomicAdd(&h[ebuf[e] >> PAYB], 1);
  __syncthreads();
  int cnt = h[t];
  __syncthreads();
  for (int o = 1; o < 512; o <<= 1){
    int tmp = (t >= o) ? h[t - o] : 0;
    __syncthreads();
    h[t] += tmp;
    __syncthreads();
  }
  int excl = h[t] - cnt;
  cur[t] = excl;
  int n = r0 + t;
  if (n < N){
    rp[n] = e0 + excl;
    if (!pool){
      float d = cnt > 0 ? rsqrtf((float)cnt) : 0.f;
      dinv[n] = d;
      if (p.xsrc[s]){                // stage 0: fused prescale xs0 = d * x row (F=3)
        const float* x = p.xsrc[s];
        p.xsdst[s][n] = make_float4(d * x[n * 3 + 0], d * x[n * 3 + 1], d * x[n * 3 + 2], 0.f);
      }
    }
  }
  __syncthreads();
  for (int e = e0 + t; e < e1; e += 512){
    unsigned u = ebuf[e];
    int pp = atomicAdd(&cur[u >> PAYB], 1);
    int dst = e0 + pp;
    if (pool){
      int ei = (int)(u & PAYM);
      cs[dst] = pcol[ei]; wv[dst] = pval[ei];
    } else {
      cs[dst] = (int)(u & PAYM);
    }
  }
}

// ================= CSR gathers (prescaled source, edge-split lanes, 2x unrolled chains) =================
__global__ __launch_bounds__(256) void k_gather3(const int* __restrict__ rp, const int* __restrict__ cs,
                          const float4* __restrict__ xs, const float* __restrict__ dinv,
                          const float* __restrict__ sub, float* __restrict__ dst,
                          float4* __restrict__ xs_out, int N, float scale){
  int tid = blockIdx.x * 256 + threadIdx.x;
  int n = tid >> 3, q = tid & 7;
  if (n >= N) return;
  int e0 = rp[n], e1 = rp[n + 1];
  float a0 = 0.f, a1 = 0.f, a2 = 0.f;
  int e = e0 + q;
  for (; e + 8 < e1; e += 16){
    int c0 = cs[e], c1 = cs[e + 8];
    float4 v0 = xs[c0];
    float4 v1 = xs[c1];
    a0 += v0.x + v1.x; a1 += v0.y + v1.y; a2 += v0.z + v1.z;
  }
  if (e < e1){
    float4 v = xs[cs[e]];
    a0 += v.x; a1 += v.y; a2 += v.z;
  }
  a0 += __shfl_xor(a0, 1); a1 += __shfl_xor(a1, 1); a2 += __shfl_xor(a2, 1);
  a0 += __shfl_xor(a0, 2); a1 += __shfl_xor(a1, 2); a2 += __shfl_xor(a2, 2);
  a0 += __shfl_xor(a0, 4); a1 += __shfl_xor(a1, 4); a2 += __shfl_xor(a2, 4);
  if (q == 0){
    float dn = dinv[n];
    float m = -scale * dn;
    float r0 = m * a0, r1 = m * a1, r2 = m * a2;
    if (sub){ r0 -= sub[n * 3 + 0]; r1 -= sub[n * 3 + 1]; r2 -= sub[n * 3 + 2]; }
    dst[n * 3 + 0] = r0; dst[n * 3 + 1] = r1; dst[n * 3 + 2] = r2;
    if (xs_out) xs_out[n] = make_float4(dn * r0, dn * r1, dn * r2, 0.f);
  }
}

template<int F>
__global__ __launch_bounds__(256) void k_gatherT(const int* __restrict__ rp, const int* __restrict__ cs,
                          const float4* __restrict__ xs, const float* __restrict__ dinv,
                          const float* __restrict__ sub, float* __restrict__ dst,
                          float4* __restrict__ xs_out, int N, float scale){
  constexpr int L = F / 4;
  constexpr int G = 4 * L;
  int tid = blockIdx.x * 256 + threadIdx.x;
  int n = tid / G, q = tid % G;
  if (n >= N) return;
  int f4 = q % L, es = q / L;
  int e0 = rp[n], e1 = rp[n + 1];
  float4 acc = make_float4(0.f, 0.f, 0.f, 0.f);
  int e = e0 + es;
  for (; e + 4 < e1; e += 8){
    int c0 = cs[e], c1 = cs[e + 4];
    float4 v0 = xs[(long)c0 * L + f4];
    float4 v1 = xs[(long)c1 * L + f4];
    acc.x += v0.x + v1.x; acc.y += v0.y + v1.y;
    acc.z += v0.z + v1.z; acc.w += v0.w + v1.w;
  }
  if (e < e1){
    float4 v = xs[(long)cs[e] * L + f4];
    acc.x += v.x; acc.y += v.y; acc.z += v.z; acc.w += v.w;
  }
  acc.x += __shfl_xor(acc.x, L);     acc.y += __shfl_xor(acc.y, L);
  acc.z += __shfl_xor(acc.z, L);     acc.w += __shfl_xor(acc.w, L);
  acc.x += __shfl_xor(acc.x, 2 * L); acc.y += __shfl_xor(acc.y, 2 * L);
  acc.z += __shfl_xor(acc.z, 2 * L); acc.w += __shfl_xor(acc.w, 2 * L);
  if (es == 0){
    float dn = dinv[n];
    float m = -scale * dn;
    float4 r = make_float4(m * acc.x, m * acc.y, m * acc.z, m * acc.w);
    if (sub){
      float4 sv = ((const float4*)sub)[(long)n * L + f4];
      r.x -= sv.x; r.y -= sv.y; r.z -= sv.z; r.w -= sv.w;
    }
    ((float4*)dst)[(long)n * L + f4] = r;
    if (xs_out) xs_out[(long)n * L + f4] = make_float4(dn * r.x, dn * r.y, dn * r.z, dn * r.w);
  }
}

// pool gather; optionally emits prescaled xs for the next graph layer
template<int F>
__global__ __launch_bounds__(256) void k_gatherP(const int* __restrict__ rp, const int* __restrict__ cs,
                          const float* __restrict__ wv, const float* __restrict__ h,
                          float* __restrict__ dst, int N,
                          const float* __restrict__ dinvN, float4* __restrict__ xsN){
  constexpr int L = F / 4;
  int tid = blockIdx.x * 256 + threadIdx.x;
  int n = tid / L, q = tid % L;
  if (n >= N) return;
  const float4* h4 = (const float4*)h;
  int e0 = rp[n], e1 = rp[n + 1];
  float4 acc = make_float4(0.f, 0.f, 0.f, 0.f);
  int e = e0;
  for (; e + 1 < e1; e += 2){
    int c0 = cs[e], c1 = cs[e + 1];
    float w0 = wv[e], w1 = wv[e + 1];
    float4 v0 = h4[(long)c0 * L + q];
    float4 v1 = h4[(long)c1 * L + q];
    acc.x = fmaf(w0, v0.x, acc.x); acc.y = fmaf(w0, v0.y, acc.y);
    acc.z = fmaf(w0, v0.z, acc.z); acc.w = fmaf(w0, v0.w, acc.w);
    acc.x = fmaf(w1, v1.x, acc.x); acc.y = fmaf(w1, v1.y, acc.y);
    acc.z = fmaf(w1, v1.z, acc.z); acc.w = fmaf(w1, v1.w, acc.w);
  }
  if (e < e1){
    int c = cs[e];
    float w = wv[e];
    float4 v = h4[(long)c * L + q];
    acc.x = fmaf(w, v.x, acc.x); acc.y = fmaf(w, v.y, acc.y);
    acc.z = fmaf(w, v.z, acc.z); acc.w = fmaf(w, v.w, acc.w);
  }
  ((float4*)dst)[(long)n * L + q] = acc;
  if (xsN){
    float dn = dinvN[n];
    xsN[(long)n * L + q] = make_float4(dn * acc.x, dn * acc.y, dn * acc.z, dn * acc.w);
  }
}

// ================= dense cheb contraction, LDS-tiled =================
template<int F, int FO, int R, bool RELU>
__global__ __launch_bounds__(256) void k_cheb_tile(const float* __restrict__ x, const float* __restrict__ T, int N,
                           const float* __restrict__ W, const float* __restrict__ b,
                           float* __restrict__ out){
  constexpr int OQ4  = FO / 4;
  constexpr int NSUB = 256 / OQ4;
  constexpr int NT   = NSUB * R;
  constexpr int F6   = KCH * F;
  int n0 = blockIdx.x * NT;
  int o4   = threadIdx.x % OQ4;
  int nsub = threadIdx.x / OQ4;
  const float4* W4 = (const float4*)W;       // [F6][OQ4]
  float4 acc[R];
  float4 bb = ((const float4*)b)[o4];
#pragma unroll
  for (int r = 0; r < R; r++) acc[r] = bb;

  if constexpr (F == 3){
    constexpr int PITCH = F6 + 2;
    __shared__ float X[NT * PITCH];
    for (int i = threadIdx.x; i < NT * F6; i += 256){
      int k = i / (NT * 3);
      int idx = i - k * (NT * 3);
      const float* src = (k == 0) ? x : (T + (size_t)(k - 1) * N * 3);
      int node = idx / 3, j = idx - node * 3;
      float v = (n0 + node < N) ? src[(long)n0 * 3 + idx] : 0.f;
      X[node * PITCH + k * 3 + j] = v;
    }
    __syncthreads();
#pragma unroll
    for (int f = 0; f < F6; f++){
      float4 w = W4[(long)f * OQ4 + o4];
#pragma unroll
      for (int r = 0; r < R; r++){
        float v = X[(nsub * R + r) * PITCH + f];
        acc[r].x = fmaf(v, w.x, acc[r].x); acc[r].y = fmaf(v, w.y, acc[r].y);
        acc[r].z = fmaf(v, w.z, acc[r].z); acc[r].w = fmaf(v, w.w, acc[r].w);
      }
    }
  } else {
    constexpr int L  = F / 4;
    constexpr int P4 = F6 / 4 + 1;
    __shared__ float4 X[NT * P4];
    for (int i = threadIdx.x; i < NT * KCH * L; i += 256){
      int k = i / (NT * L);
      int idx = i - k * (NT * L);
      int node = idx / L, q = idx - node * L;
      const float4* src4 = (const float4*)((k == 0) ? x : (T + (size_t)(k - 1) * N * F));
      float4 v = make_float4(0.f, 0.f, 0.f, 0.f);
      if (n0 + node < N) v = src4[(long)n0 * L + idx];
      X[node * P4 + k * L + q] = v;
    }
    __syncthreads();
#pragma unroll 4
    for (int f4 = 0; f4 < F6 / 4; f4++){
      float4 w0 = W4[(long)(4 * f4 + 0) * OQ4 + o4];
      float4 w1 = W4[(long)(4 * f4 + 1) * OQ4 + o4];
      float4 w2 = W4[(long)(4 * f4 + 2) * OQ4 + o4];
      float4 w3 = W4[(long)(4 * f4 + 3) * OQ4 + o4];
#pragma unroll
      for (int r = 0; r < R; r++){
        float4 hv = X[(nsub * R + r) * P4 + f4];
        acc[r].x = fmaf(hv.x, w0.x, acc[r].x); acc[r].y = fmaf(hv.x, w0.y, acc[r].y);
        acc[r].z = fmaf(hv.x, w0.z, acc[r].z); acc[r].w = fmaf(hv.x, w0.w, acc[r].w);
        acc[r].x = fmaf(hv.y, w1.x, acc[r].x); acc[r].y = fmaf(hv.y, w1.y, acc[r].y);
        acc[r].z = fmaf(hv.y, w1.z, acc[r].z); acc[r].w = fmaf(hv.y, w1.w, acc[r].w);
        acc[r].x = fmaf(hv.z, w2.x, acc[r].x); acc[r].y = fmaf(hv.z, w2.y, acc[r].y);
        acc[r].z = fmaf(hv.z, w2.z, acc[r].z); acc[r].w = fmaf(hv.z, w2.w, acc[r].w);
        acc[r].x = fmaf(hv.w, w3.x, acc[r].x); acc[r].y = fmaf(hv.w, w3.y, acc[r].y);
        acc[r].z = fmaf(hv.w, w3.z, acc[r].z); acc[r].w = fmaf(hv.w, w3.w, acc[r].w);
      }
    }
  }

#pragma unroll
  for (int r = 0; r < R; r++){
    int n = n0 + nsub * R + r;
    if (n < N){
      float4 o = acc[r];
      if (RELU){
        o.x = fmaxf(o.x, 0.f); o.y = fmaxf(o.y, 0.f);
        o.z = fmaxf(o.z, 0.f); o.w = fmaxf(o.w, 0.f);
      }
      ((float4*)out)[(long)n * OQ4 + o4] = o;
    }
  }
}

// ================= hidden GEMM + global max (round-16 best: 256 thr, HNT=8) =================
#define HNT 8
__global__ __launch_bounds__(256) void k_hidden1(const float* __restrict__ h2, const float* __restrict__ Wh,
                                                 float4* __restrict__ pmax, int N){
  __shared__ float4 sh4[HNT * 32];       // 4 KB: 8 nodes x 32 float4
  int n0 = blockIdx.x * HNT;
  for (int i = threadIdx.x; i < HNT * 32; i += 256){
    int n = i >> 5;
    float4 v = make_float4(0.f, 0.f, 0.f, 0.f);
    if (n0 + n < N) v = ((const float4*)h2)[(long)(n0 + n) * 32 + (i & 31)];
    sh4[i] = v;
  }
  __syncthreads();
  int o4 = threadIdx.x;                  // all 256 float4 outputs per block
  const float4* Wh4 = (const float4*)Wh;
  float4 acc[HNT];
#pragma unroll
  for (int j = 0; j < HNT; j++) acc[j] = make_float4(0.f, 0.f, 0.f, 0.f);
#pragma unroll 2
  for (int f4 = 0; f4 < 32; f4++){
    float4 w0 = Wh4[(long)(4 * f4 + 0) * 256 + o4];
    float4 w1 = Wh4[(long)(4 * f4 + 1) * 256 + o4];
    float4 w2 = Wh4[(long)(4 * f4 + 2) * 256 + o4];
    float4 w3 = Wh4[(long)(4 * f4 + 3) * 256 + o4];
#pragma unroll
    for (int j = 0; j < HNT; j++){
      float4 hv = sh4[j * 32 + f4];
      acc[j].x = fmaf(hv.x, w0.x, acc[j].x); acc[j].y = fmaf(hv.x, w0.y, acc[j].y);
      acc[j].z = fmaf(hv.x, w0.z, acc[j].z); acc[j].w = fmaf(hv.x, w0.w, acc[j].w);
      acc[j].x = fmaf(hv.y, w1.x, acc[j].x); acc[j].y = fmaf(hv.y, w1.y, acc[j].y);
      acc[j].z = fmaf(hv.y, w1.z, acc[j].z); acc[j].w = fmaf(hv.y, w1.w, acc[j].w);
      acc[j].x = fmaf(hv.z, w2.x, acc[j].x); acc[j].y = fmaf(hv.z, w2.y, acc[j].y);
      acc[j].z = fmaf(hv.z, w2.z, acc[j].z); acc[j].w = fmaf(hv.z, w2.w, acc[j].w);
      acc[j].x = fmaf(hv.w, w3.x, acc[j].x); acc[j].y = fmaf(hv.w, w3.y, acc[j].y);
      acc[j].z = fmaf(hv.w, w3.z, acc[j].z); acc[j].w = fmaf(hv.w, w3.w, acc[j].w);
    }
  }
  float4 m = make_float4(-INFINITY, -INFINITY, -INFINITY, -INFINITY);
#pragma unroll
  for (int j = 0; j < HNT; j++){
    if (n0 + j < N){
      m.x = fmaxf(m.x, acc[j].x); m.y = fmaxf(m.y, acc[j].y);
      m.z = fmaxf(m.z, acc[j].z); m.w = fmaxf(m.w, acc[j].w);
    }
  }
  pmax[(long)blockIdx.x * 256 + o4] = m;   // coalesced, atomic-free
}

// 32 blocks x 256 threads: block handles 8 float4 outputs; 32 row-lanes each.
__global__ __launch_bounds__(256) void k_hidden2(const float4* __restrict__ pmax, const float* __restrict__ bh,
                                                 float* __restrict__ maxed, int nb){
  __shared__ float4 red[256];
  int lo4 = threadIdx.x & 7;
  int rl  = threadIdx.x >> 3;
  int o4  = blockIdx.x * 8 + lo4;
  float4 m = make_float4(-INFINITY, -INFINITY, -INFINITY, -INFINITY);
  for (int r = rl; r < nb; r += 32){
    float4 v = pmax[(long)r * 256 + o4];
    m.x = fmaxf(m.x, v.x); m.y = fmaxf(m.y, v.y);
    m.z = fmaxf(m.z, v.z); m.w = fmaxf(m.w, v.w);
  }
  red[threadIdx.x] = m;
  __syncthreads();
  for (int off = 128; off >= 8; off >>= 1){
    if (threadIdx.x < off){
      float4 o = red[threadIdx.x + off];
      float4 c = red[threadIdx.x];
      c.x = fmaxf(c.x, o.x); c.y = fmaxf(c.y, o.y);
      c.z = fmaxf(c.z, o.z); c.w = fmaxf(c.w, o.w);
      red[threadIdx.x] = c;
    }
    __syncthreads();
  }
  if (threadIdx.x < 8){
    float4 mm = red[threadIdx.x];
    float4 b4 = ((const float4*)bh)[o4];
    ((float4*)maxed)[o4] = make_float4(mm.x + b4.x, mm.y + b4.y, mm.z + b4.z, mm.w + b4.w);
  }
}

__global__ __launch_bounds__(64) void k_final(const float* __restrict__ maxed, const float* __restrict__ Wl,
                        const float* __restrict__ bl, float* __restrict__ out){
  int c = blockIdx.x;
  int l = threadIdx.x;
  float acc = 0.f;
  for (int o = l; o < 1024; o += 64)
    acc = fmaf(maxed[o], Wl[o * NCLS + c], acc);
  for (int off = 32; off > 0; off >>= 1)
    acc += __shfl_down(acc, off);
  if (l == 0) out[c] = acc + bl[c];
}

// ================= flow drivers (xs already prescaled) =================
template<int F, int FO, int R, bool RELU>
static void run_flowT(const int* rp, const int* cs, const float* dinv, int N,
                      const float* x, const float* W, const float* b, float* out,
                      float* T, float4* xin, float4* xout, hipStream_t s){
  const float* sub = nullptr; float scale = 1.f;
  const float* srcRaw = x;
  for (int k = 1; k < KCH; k++){
    float* Tk = T + (size_t)(k - 1) * N * F;
    float4* xo = (k == KCH - 1) ? nullptr : xout;
    k_gatherT<F><<<cdiv((long)N * F, 256), 256, 0, s>>>(rp, cs, xin, dinv, sub, Tk, xo, N, scale);
    sub = srcRaw; srcRaw = Tk; scale = 2.f;
    float4* t = xin; xin = xout; xout = t;
  }
  constexpr int NTC = (256 / (FO / 4)) * R;
  k_cheb_tile<F, FO, R, RELU><<<cdiv(N, NTC), 256, 0, s>>>(x, T, N, W, b, out);
}

extern "C" void kernel_launch(void* const* d_in, const int* in_sizes, int n_in,
                              void* d_out, int out_size, void* d_ws, size_t ws_size,
                              hipStream_t stream){
  const float* pos = (const float*)d_in[0];
  const int*   ei0 = (const int*)d_in[1];
  const int*   ei1 = (const int*)d_in[2];
  const int*   ei2 = (const int*)d_in[3];
  const int*   p0r = (const int*)d_in[4];
  const int*   p0c = (const int*)d_in[5];
  const float* p0v = (const float*)d_in[6];
  const int*   p1r = (const int*)d_in[7];
  const int*   p1c = (const int*)d_in[8];
  const float* p1v = (const float*)d_in[9];
  const float* W0  = (const float*)d_in[10]; const float* b0 = (const float*)d_in[11];
  const float* W1  = (const float*)d_in[12]; const float* b1 = (const float*)d_in[13];
  const float* W2  = (const float*)d_in[14]; const float* b2 = (const float*)d_in[15];
  const float* Wh  = (const float*)d_in[16]; const float* bh = (const float*)d_in[17];
  const float* Wl  = (const float*)d_in[18]; const float* bl = (const float*)d_in[19];
  float* out = (float*)d_out;

  // ---- workspace layout (float units), ~12.33M floats ----
  float* TB = (float*)d_ws;                  // 4.0M : ebufs (build) overlay; per-layer T region; pmax overlay
  float* hA = TB + 4000000;                  // 3.2M : L0 out [N0,32]; L1 out; L2 out [N2,128]
  float* hB = hA + 3200000;                  // 1.6M : xs ping-pong regions
  float* hC = hB + 1600000;                  // 0.8M : pool outs [N1,32]/[N2,64]
  int* cs0   = (int*)(hC + 800000);          // 1.6M
  int* cs1   = cs0 + 1600000;                // 400K
  int* cs2   = cs1 + 400000;                 // 100K
  int* csP0  = cs2 + 100000;                 // 100K
  int* csP1  = csP0 + 100000;                // 25K
  float* wvP0 = (float*)(csP1 + 25000);      // 100K
  float* wvP1 = wvP0 + 100000;               // 25K
  int* rp0  = (int*)(wvP1 + 25000);          // 100001
  int* rp1  = rp0 + 100001;                  // 25001
  int* rp2  = rp1 + 25001;                   // 6251
  int* rpP0 = rp2 + 6251;                    // 25001
  int* rpP1 = rpP0 + 25001;                  // 6251
  float* dv0 = (float*)(rpP1 + 6251);        // 100000
  float* dv1 = dv0 + 100000;                 // 25000
  float* dv2 = dv1 + 25000;                  // 6250
  int* gh   = (int*)(dv2 + 6250);            // 76800
  int* bsum = gh + 76800;                    // 80
  float* maxed = (float*)(bsum + 80);        // 1024

  // ebufs overlay the TB region (dead before any gather/T write)
  unsigned* eb0  = (unsigned*)TB;            // 1.6M
  unsigned* eb1  = eb0 + 1600000;            // 400K
  unsigned* eb2  = eb1 + 400000;             // 100K
  unsigned* ebP0 = eb2 + 100000;             // 100K
  unsigned* ebP1 = ebP0 + 100000;            // 25K

  // ---- batched CSR builds (stage 0 fuses xs0 = dinv*pos into hB) ----
  BP bp{};
  const int* rows[NST] = {ei0, ei1, ei2, p0r, p1r};
  const int* cols[NST] = {ei0 + E0G, ei1 + E1G, ei2 + E2G, p0c, p1c};
  const float* pvals[NST] = {nullptr, nullptr, nullptr, p0v, p1v};
  unsigned* ebufs[NST] = {eb0, eb1, eb2, ebP0, ebP1};
  int* css[NST] = {cs0, cs1, cs2, csP0, csP1};
  float* wvs[NST] = {nullptr, nullptr, nullptr, wvP0, wvP1};
  int* rps[NST] = {rp0, rp1, rp2, rpP0, rpP1};
  float* dvs[NST] = {dv0, dv1, dv2, nullptr, nullptr};
  int Es[NST] = {E0G, E1G, E2G, N0G, N1G};
  int Ns[NST] = {N0G, N1G, N2G, N1G, N2G};
  int pools[NST] = {0, 0, 0, 1, 1};
  int ghacc = 0, scanacc = 0, bacc = 0;
  bp.blkS[0] = 0; bp.blkB[0] = 0;
  for (int s = 0; s < NST; s++){
    bp.row[s] = rows[s]; bp.col[s] = cols[s]; bp.pval[s] = pvals[s];
    bp.ebuf[s] = ebufs[s]; bp.cs[s] = css[s]; bp.wv[s] = wvs[s];
    bp.rp[s] = rps[s]; bp.dinv[s] = dvs[s];
    bp.xsrc[s] = (s == 0) ? pos : nullptr;
    bp.xsdst[s] = (s == 0) ? (float4*)hB : nullptr;
    bp.E[s] = Es[s]; bp.N[s] = Ns[s]; bp.pool[s] = pools[s];
    bp.nbkt[s] = cdiv(Ns[s], RPB);
    bp.chunk[s] = cdiv(Es[s], NBLK);
    bp.ghoff[s] = ghacc; ghacc += bp.nbkt[s] * NBLK;
    bp.nb[s] = cdiv(bp.nbkt[s] * NBLK, SCB);
    bp.bsumoff[s] = s * 16;
    scanacc += bp.nb[s]; bp.blkS[s + 1] = scanacc;
    bacc += bp.nbkt[s]; bp.blkB[s + 1] = bacc;
  }

  k_phist_b<<<NST * NBLK, 256, 0, stream>>>(bp, gh);
  k_scanA_b<<<scanacc, 256, 0, stream>>>(bp, gh, bsum);
  k_scanC_b<<<scanacc, 256, 0, stream>>>(bp, gh, bsum);
  k_pscatter_b<<<NST * NBLK, 256, 0, stream>>>(bp, gh);
  k_bfinal_b<<<bacc, 512, 0, stream>>>(bp, gh);

  // ---- layer 0: cheb(pos) -> hA [N0,32]; T=1.5M in TB; xs ping-pong in hB (xs0 pre-filled) ----
  {
    float4* xin = (float4*)hB; float4* xout = (float4*)(hB + 400000);
    const float* sub = nullptr; float scale = 1.f;
    const float* srcRaw = pos;
    for (int k = 1; k < KCH; k++){
      float* Tk = TB + (size_t)(k - 1) * N0G * 3;
      float4* xo = (k == KCH - 1) ? nullptr : xout;
      k_gather3<<<cdiv((long)N0G * 8, 256), 256, 0, stream>>>(rp0, cs0, xin, dv0, sub, Tk, xo, N0G, scale);
      sub = srcRaw; srcRaw = Tk; scale = 2.f;
      float4* t = xin; xin = xout; xout = t;
    }
    k_cheb_tile<3, 32, 2, true><<<cdiv(N0G, 64), 256, 0, stream>>>(pos, TB, N0G, W0, b0, hA);
  }

  // ---- pool 0: hA -> hC [N1,32]; fused prescale xs1 = dv1*out -> hB ----
  k_gatherP<32><<<cdiv((long)N1G * 8, 256), 256, 0, stream>>>(rpP0, csP0, wvP0, hA, hC, N1G,
                                                              dv1, (float4*)hB);

  // ---- layer 1: cheb(hC) -> hA [N1,64]; T=4.0M in TB; xs ping-pong hB/hB+800K ----
  run_flowT<32, 64, 2, true>(rp1, cs1, dv1, N1G, hC, W1, b1, hA,
                             TB, (float4*)hB, (float4*)(hB + 800000), stream);

  // ---- pool 1: hA -> hC [N2,64]; fused prescale xs2 = dv2*out -> hB ----
  k_gatherP<64><<<cdiv((long)N2G * 16, 256), 256, 0, stream>>>(rpP1, csP1, wvP1, hA, hC, N2G,
                                                               dv2, (float4*)hB);

  // ---- layer 2: cheb(hC) -> hA [N2,128]; T=2.0M in TB; xs ping-pong hB/hB+400K ----
  run_flowT<64, 128, 2, false>(rp2, cs2, dv2, N2G, hC, W2, b2, hA,
                               TB, (float4*)hB, (float4*)(hB + 400000), stream);

  // ---- hidden GEMM + global max: h2 read once, pmax overlay on TB (dead) ----
  int nbH = cdiv(N2G, HNT);                  // 782 blocks
  float4* pmax = (float4*)TB;                // 782*256 float4 = 3.2 MB, fits in TB
  k_hidden1<<<nbH, 256, 0, stream>>>(hA, Wh, pmax, N2G);
  k_hidden2<<<32, 256, 0, stream>>>(pmax, bh, maxed, nbH);

  // ---- classifier ----
  k_final<<<NCLS, 64, 0, stream>>>(maxed, Wl, bl, out);
}